// Round 6
// baseline (317.573 us; speedup 1.0000x reference)
//
#include <hip/hip_runtime.h>

#define DEVFN __device__ __forceinline__

typedef __attribute__((ext_vector_type(8))) __bf16 bf16x8;
typedef __attribute__((ext_vector_type(16))) float f32x16;
typedef unsigned short ushort;

DEVFN float sigmoidf_(float x) { return 1.f / (1.f + __expf(-x)); }

DEVFN ushort f2bf(float f) {   // RNE float->bf16
    unsigned u = __float_as_uint(f);
    unsigned r = (u + 0x7FFF + ((u >> 16) & 1)) >> 16;
    return (ushort)r;
}

// ---------------- correlation: depth-2 software-pipelined, slice-store -------
// Thread owns 4 px. Channel loop alternates two register sets (A/B): loads of
// channel c+1 issue while FMAs of channel c run -> ~10KB/wave in flight.
template<int C, int CC, int H, int W, int NOFF, int OFS>
__global__ __launch_bounds__(256, 2) void corr_kernel(const float* __restrict__ f1,
                                                      const float* __restrict__ f2,
                                                      float* __restrict__ slices) {
    constexpr int HW = H * W;
    constexpr int WINSZ = NOFF + 3;
    const int t     = threadIdx.x;
    const int px    = blockIdx.x * 1024 + t * 4;
    const int b     = blockIdx.y;
    const int chunk = blockIdx.z;
    const int y  = px / W;
    const int x0 = px - y * W;

    const float* f1p = f1 + ((size_t)b * C + chunk * CC) * HW + px;
    const float* f2b = f2 + ((size_t)b * C + chunk * CC) * HW;

    bool rv[NOFF]; const float* rp[NOFF];
#pragma unroll
    for (int d = 0; d < NOFF; ++d) {
        int yy = y + d - OFS;
        rv[d] = (yy >= 0) && (yy < H);
        rp[d] = f2b + (size_t)(rv[d] ? yy : 0) * W + x0;
    }
    const bool lok = x0 >= 4;
    const bool hok = (x0 + 4) < W;

    float acc[NOFF][NOFF][4];
#pragma unroll
    for (int i = 0; i < NOFF; ++i)
#pragma unroll
        for (int j = 0; j < NOFF; ++j)
#pragma unroll
            for (int p = 0; p < 4; ++p) acc[i][j][p] = 0.f;

#define CORR_LOAD(cc_, F1V, WIN) {                                                            \
    *reinterpret_cast<float4*>(F1V) = *reinterpret_cast<const float4*>(f1p + (size_t)(cc_) * HW); \
    _Pragma("unroll")                                                                         \
    for (int d_ = 0; d_ < NOFF; ++d_) {                                                       \
        const float* r_ = rp[d_] + (size_t)(cc_) * HW;                                        \
        const float4 z4_ = make_float4(0.f, 0.f, 0.f, 0.f);                                   \
        if constexpr (OFS == 2) {                                                             \
            float4 lo_ = (rv[d_] && lok) ? *reinterpret_cast<const float4*>(r_ - 4) : z4_;    \
            float4 md_ = rv[d_] ? *reinterpret_cast<const float4*>(r_) : z4_;                 \
            float  hv_ = (rv[d_] && hok) ? r_[4] : 0.f;                                       \
            WIN[d_][0] = lo_.z; WIN[d_][1] = lo_.w; WIN[d_][2] = md_.x; WIN[d_][3] = md_.y;   \
            WIN[d_][4] = md_.z; WIN[d_][5] = md_.w; WIN[d_][6] = hv_;                         \
        } else {                                                                              \
            float  lv_ = (rv[d_] && lok) ? r_[-1] : 0.f;                                      \
            float4 md_ = rv[d_] ? *reinterpret_cast<const float4*>(r_) : z4_;                 \
            WIN[d_][0] = lv_; WIN[d_][1] = md_.x; WIN[d_][2] = md_.y; WIN[d_][3] = md_.z;     \
            WIN[d_][4] = md_.w;                                                               \
        }                                                                                     \
    } }

#define CORR_FMA(F1V, WIN) {                                                                  \
    _Pragma("unroll") for (int d_ = 0; d_ < NOFF; ++d_)                                       \
    _Pragma("unroll") for (int dx_ = 0; dx_ < NOFF; ++dx_)                                    \
    _Pragma("unroll") for (int p_ = 0; p_ < 4; ++p_)                                          \
        acc[d_][dx_][p_] = fmaf(F1V[p_], WIN[d_][p_ + dx_], acc[d_][dx_][p_]); }

    float f1A[4], f1B[4];
    float winA[NOFF][WINSZ], winB[NOFF][WINSZ];
    CORR_LOAD(0, f1A, winA);
#pragma unroll
    for (int c = 0; c < CC; c += 2) {
        if (c + 1 < CC) CORR_LOAD(c + 1, f1B, winB);
        CORR_FMA(f1A, winA);
        if (c + 2 < CC) CORR_LOAD(c + 2, f1A, winA);
        if (c + 1 < CC) CORR_FMA(f1B, winB);
    }
#undef CORR_LOAD
#undef CORR_FMA

    float* ao = slices + ((size_t)(chunk * 2 + b) * NOFF * NOFF) * HW + px;
#pragma unroll
    for (int dyi = 0; dyi < NOFF; ++dyi)
#pragma unroll
        for (int dxi = 0; dxi < NOFF; ++dxi)
            *reinterpret_cast<float4*>(ao + (size_t)(dyi * NOFF + dxi) * HW) =
                make_float4(acc[dyi][dxi][0], acc[dyi][dxi][1], acc[dyi][dxi][2], acc[dyi][dxi][3]);
}

// ---------------- slice reduction: base[i] = sum_s slices[s*STRIDE + i] ------
template<int S, int STRIDE>
__global__ void reduce_kernel(const float* __restrict__ in, float* __restrict__ out) {
    const int i = (blockIdx.x * 256 + threadIdx.x) * 4;
    if (i >= STRIDE) return;
    float sx = 0.f, sy = 0.f, sz = 0.f, sw = 0.f;
#pragma unroll 8
    for (int k = 0; k < S; ++k) {
        float4 v = *reinterpret_cast<const float4*>(in + (size_t)k * STRIDE + i);
        sx += v.x; sy += v.y; sz += v.z; sw += v.w;
    }
    *reinterpret_cast<float4*>(out + i) = make_float4(sx, sy, sz, sw);
}

// ---------------- build conv input: Xin[b][icg8][y][x][ic16] bf16 ------------
template<int H, int W, int SCALE, int SHIFT, int NOFF, int OFS>
__global__ void xbuild_kernel(const float* __restrict__ base, const float* __restrict__ h_pre,
                              ushort* __restrict__ Xin) {
    const int HW = H * W;
    int i = blockIdx.x * 256 + threadIdx.x;
    if (i >= 2 * HW * 16) return;
    int g  = i & 15;                 // 8-ic group 0..15
    int px = (i >> 4) % HW;
    int b  = (i >> 4) / HW;
    int y = px / W, x = px - y * W;
    ushort out8[8];
#pragma unroll
    for (int j = 0; j < 8; ++j) {
        int ic = g * 8 + j;
        float v = 0.f;
        if (ic < 49) {
            int pi = ic / 7, pj = ic - pi * 7;
            int dy = pi - 3, dx = pj - 3;
            int uy = SCALE * y + dy, ux = SCALE * x + dx;
            if (uy >= 0 && uy < SCALE * H && ux >= 0 && ux < SCALE * W) {
                int idy = (dy >> SHIFT) + OFS;
                int idx = (dx >> SHIFT) + OFS;
                float cv = base[((size_t)b * NOFF * NOFF + idy * NOFF + idx) * HW + px];
                v = cv >= 0.f ? cv : 0.01f * cv;
            }
        } else if (ic < 98) {
            v = h_pre[((size_t)b * 49 + (ic - 49)) * HW + px];
        }
        out8[j] = f2bf(v);
    }
    // px-major layout: [b][icg16][y][x][16], this thread writes half a 16-chunk
    size_t off = (((size_t)b * 8 + (g >> 1)) * HW + px) * 16 + (g & 1) * 8;
    *reinterpret_cast<uint4*>(Xin + off) = *reinterpret_cast<uint4*>(out8);
}

// ---------------- weight prep: Wmf[tap9][icg16][oc256][8] bf16 (both levels) ----
__global__ void wprep_kernel(const float* __restrict__ w0, const float* __restrict__ w1,
                             ushort* __restrict__ Wmf0, ushort* __restrict__ Wmf1) {
    const float* w = blockIdx.y ? w1 : w0;
    ushort* Wmf    = blockIdx.y ? Wmf1 : Wmf0;
    int i = blockIdx.x * 256 + threadIdx.x;
    const int n = 9 * 16 * 256 * 8;
    if (i >= n) return;
    int iEl = i & 7;
    int oc  = (i >> 3) & 255;
    int icg = (i >> 11) & 15;
    int tap = i >> 15;
    int ic  = icg * 8 + iEl;
    float v = (oc < 196 && ic < 98) ? w[((size_t)oc * 98 + ic) * 9 + tap] : 0.f;
    Wmf[i] = f2bf(v);
}

// ---------------- conv3x3 via mfma_f32_32x32x16_bf16, no LDS, no barriers ----
// Weights preloaded in VGPRs; X read direct from global (L2-resident, px-major).
template<int H, int W, int SPLIT, int ICPS, int NKC>
__global__ __launch_bounds__(256, 2) void convmf_kernel(const ushort* __restrict__ Xin,
                                                        const ushort* __restrict__ Wmf,
                                                        float* __restrict__ Y) {
    const int HW = H * W;
    const int tilesx = W / 16;
    const int by0 = (blockIdx.x / tilesx) * 8;
    const int bx0 = (blockIdx.x % tilesx) * 16;
    const int ocb = blockIdx.y * 64;
    const int b   = blockIdx.z & 1;
    const int s   = blockIdx.z >> 1;
    const int t   = threadIdx.x;
    const int wv  = t >> 6;
    const int l   = t & 63;
    const int n    = l & 31;
    const int hi   = l >> 5;
    const int wrow = 2 * wv + (n >> 4);
    const int wcol = n & 15;

    f32x16 acc0 = {};
    f32x16 acc1 = {};

#pragma unroll
    for (int kc = 0; kc < NKC; ++kc) {
        const int icg8  = (s * ICPS + kc * 16) / 8 + hi;
        const int icg16 = (s * ICPS) / 16 + kc;
        const ushort* wp = Wmf + ((size_t)icg8 * 256 + ocb + n) * 8;
        const ushort* xb = Xin + ((size_t)b * 8 + icg16) * HW * 16 + hi * 8;
#pragma unroll
        for (int j = 0; j < 9; ++j) {
            const int ky = j / 3, kx = j - ky * 3;
            bf16x8 a0 = *reinterpret_cast<const bf16x8*>(wp + (size_t)j * 16 * 256 * 8);
            bf16x8 a1 = *reinterpret_cast<const bf16x8*>(wp + (size_t)j * 16 * 256 * 8 + 32 * 8);
            const int gy = by0 + wrow + ky - 1;
            const int gx = bx0 + wcol + kx - 1;
            bf16x8 bfr = {};
            if (gy >= 0 && gy < H && gx >= 0 && gx < W)
                bfr = *reinterpret_cast<const bf16x8*>(xb + (size_t)(gy * W + gx) * 16);
            acc0 = __builtin_amdgcn_mfma_f32_32x32x16_bf16(a0, bfr, acc0, 0, 0, 0);
            acc1 = __builtin_amdgcn_mfma_f32_32x32x16_bf16(a1, bfr, acc1, 0, 0, 0);
        }
    }

    float* Yo = Y + ((size_t)(s * 2 + b) * 196) * HW;
    const int po = (by0 + wrow) * W + bx0 + wcol;
#pragma unroll
    for (int r = 0; r < 16; ++r) {
        int m = (r & 3) + 8 * (r >> 2) + 4 * hi;
        int oc0 = ocb + m;
        if (oc0 < 196) Yo[(size_t)oc0 * HW + po] = acc0[r];
        int oc1 = ocb + 32 + m;
        if (oc1 < 196) Yo[(size_t)oc1 * HW + po] = acc1[r];
    }
}

// ---------------- LSTM gates (split-reduce + bias + elementwise) ----------------
template<int S, int HW>
__global__ void lstm_kernel(const float* __restrict__ Y, const float* __restrict__ bias,
                            const float* __restrict__ c_pre,
                            float* __restrict__ h_out, float* __restrict__ c_out) {
    int i = blockIdx.x * 256 + threadIdx.x;
    const int n = 2 * 49 * HW;
    if (i >= n) return;
    int b   = i / (49 * HW);
    int rem = i - b * (49 * HW);
    int k   = rem / HW;
    float g4[4];
#pragma unroll
    for (int gi = 0; gi < 4; ++gi) {
        float v = bias[gi * 49 + k];
#pragma unroll
        for (int ss = 0; ss < S; ++ss)
            v += Y[((size_t)((ss * 2 + b) * 196) + gi * 49) * HW + rem];
        g4[gi] = v;
    }
    float iv = sigmoidf_(g4[0]);
    float fv = sigmoidf_(g4[1]);
    float ov = sigmoidf_(g4[2]);
    float gv = tanhf(g4[3]);
    float cp = c_pre[i];
    float cn = fv * cp + iv * gv;
    h_out[i] = ov * tanhf(cn);
    c_out[i] = cn;
}

extern "C" void kernel_launch(void* const* d_in, const int* in_sizes, int n_in,
                              void* d_out, int out_size, void* d_ws, size_t ws_size,
                              hipStream_t stream) {
    (void)in_sizes; (void)n_in; (void)out_size; (void)ws_size;
    const float* x0  = (const float*)d_in[0];
    const float* x1  = (const float*)d_in[1];
    const float* xp0 = (const float*)d_in[2];
    const float* xp1 = (const float*)d_in[3];
    const float* h0  = (const float*)d_in[4];
    const float* c0  = (const float*)d_in[5];
    const float* h1  = (const float*)d_in[6];
    const float* c1  = (const float*)d_in[7];
    const float* w0  = (const float*)d_in[8];
    const float* b0  = (const float*)d_in[9];
    const float* w1  = (const float*)d_in[10];
    const float* b1  = (const float*)d_in[11];
    float* out = (float*)d_out;

    // workspace layout (floats) — identical footprint to round 5 (23.6 MB)
    float* ws = (float*)d_ws;
    float*  Wmf0f = ws;                  // 147456
    float*  Wmf1f = Wmf0f + 147456;      // 147456
    float*  Xin0f = Wmf1f + 147456;      // 524288
    float*  Xin1f = Xin0f + 524288;      // 131072
    float*  base0 = Xin1f + 131072;      // 131072 (2b*16off*4096)
    float*  base1 = base0 + 131072;      // 8192   (2b*4off*1024)
    float*  Y0    = base1 + 8192;        // 3211264 (2sp*2b*196*4096)
    float*  Y1    = Y0 + 3211264;        // 1605632 (4sp*2b*196*1024)
    // corr slice buffers alias the Y region (consumed by reduce before conv writes Y)
    float*  slc0  = Y0;                  // 32 chunks * 2b*16off*4096 = 4194304
    float*  slc1  = Y0 + 4194304;        // 64 chunks * 2b*4off*1024  = 524288 (ends 4718592 <= 4816896)
    ushort* Wmf0 = (ushort*)Wmf0f;
    ushort* Wmf1 = (ushort*)Wmf1f;
    ushort* Xin0 = (ushort*)Xin0f;
    ushort* Xin1 = (ushort*)Xin1f;

    // level 0: C=512, CC=16 -> 32 chunks; level 1: C=1024, CC=16 -> 64 chunks
    corr_kernel<512, 16, 64, 64, 4, 2><<<dim3(4, 2, 32), 256, 0, stream>>>(x0, xp0, slc0);
    corr_kernel<1024, 16, 32, 32, 2, 1><<<dim3(1, 2, 64), 256, 0, stream>>>(x1, xp1, slc1);

    reduce_kernel<32, 131072><<<128, 256, 0, stream>>>(slc0, base0);
    reduce_kernel<64, 8192><<<8, 256, 0, stream>>>(slc1, base1);

    wprep_kernel<<<dim3(1152, 2), 256, 0, stream>>>(w0, w1, Wmf0, Wmf1);

    xbuild_kernel<64, 64, 2, 1, 4, 2><<<512, 256, 0, stream>>>(base0, h0, Xin0);
    xbuild_kernel<32, 32, 4, 2, 2, 1><<<128, 256, 0, stream>>>(base1, h1, Xin1);

    // conv level 0: SPLIT=2 (64 ic), NKC=4; grid (32 px-tiles, 4 ocb, 2b*2s)
    convmf_kernel<64, 64, 2, 64, 4><<<dim3(32, 4, 4), 256, 0, stream>>>(Xin0, Wmf0, Y0);
    // conv level 1: SPLIT=4 (32 ic), NKC=2; grid (8 px-tiles, 4 ocb, 2b*4s)
    convmf_kernel<32, 32, 4, 32, 2><<<dim3(8, 4, 8), 256, 0, stream>>>(Xin1, Wmf1, Y1);

    lstm_kernel<2, 4096><<<1568, 256, 0, stream>>>(Y0, b0, c0, out + 0,      out + 401408);
    lstm_kernel<4, 1024><<<392,  256, 0, stream>>>(Y1, b1, c1, out + 802816, out + 903168);
}

// Round 8
// 189.371 us; speedup vs baseline: 1.6770x; 1.6770x over previous
//
#include <hip/hip_runtime.h>

#define DEVFN __device__ __forceinline__

typedef __attribute__((ext_vector_type(8))) __bf16 bf16x8;
typedef __attribute__((ext_vector_type(16))) float f32x16;
typedef unsigned short ushort;

DEVFN float sigmoidf_(float x) { return 1.f / (1.f + __expf(-x)); }

DEVFN ushort f2bf(float f) {   // RNE float->bf16
    unsigned u = __float_as_uint(f);
    unsigned r = (u + 0x7FFF + ((u >> 16) & 1)) >> 16;
    return (ushort)r;
}

// ---------------- correlation: clamped unconditional loads, masked store -----
// Thread owns 4 px. Per channel: f1 float4 + per-dy {float2,float4,scalar}
// clamped loads (no branches). OOB garbage is zeroed by the per-entry mask at
// the final store (each output entry's row/col is uniform across its sum).
template<int C, int CC, int H, int W, int NOFF, int OFS>
__global__ __launch_bounds__(256, 1) void corr_kernel(const float* __restrict__ f1,
                                                      const float* __restrict__ f2,
                                                      float* __restrict__ slices) {
    constexpr int HW = H * W;
    constexpr int WIN = NOFF + 3;
    const int t     = threadIdx.x;
    const int px    = blockIdx.x * 1024 + t * 4;
    const int b     = blockIdx.y;
    const int chunk = blockIdx.z;
    const int y  = px / W;
    const int x0 = px - y * W;

    const float* f1p    = f1 + ((size_t)b * C + chunk * CC) * HW + px;
    const float* f2b    = f2 + ((size_t)b * C + chunk * CC) * HW;
    const float* f2lo   = f2;                              // global start
    const float* f2hi   = f2 + (size_t)2 * C * HW - 2;     // last safe scalar/float2 base

    int   yc[NOFF];
    float rm[NOFF];
#pragma unroll
    for (int d = 0; d < NOFF; ++d) {
        int yy = y + d - OFS;
        rm[d] = (yy >= 0 && yy < H) ? 1.f : 0.f;
        yc[d] = yy < 0 ? 0 : (yy >= H ? H - 1 : yy);
    }

    float acc[NOFF][NOFF][4];
#pragma unroll
    for (int i = 0; i < NOFF; ++i)
#pragma unroll
        for (int j = 0; j < NOFF; ++j)
#pragma unroll
            for (int p = 0; p < 4; ++p) acc[i][j][p] = 0.f;

#pragma unroll 2
    for (int c = 0; c < CC; ++c) {
        float f1a[4];
        *reinterpret_cast<float4*>(f1a) = *reinterpret_cast<const float4*>(f1p + (size_t)c * HW);
        float w[NOFF][WIN];
#pragma unroll
        for (int d = 0; d < NOFF; ++d) {
            const float* r = f2b + (size_t)c * HW + yc[d] * W + x0;
            if constexpr (OFS == 2) {
                const float* plo = (r - 2 < f2lo) ? f2lo : (r - 2);
                const float* phi = (r + 4 > f2hi) ? f2hi : (r + 4);
                float2 lo = *reinterpret_cast<const float2*>(plo);
                float4 md = *reinterpret_cast<const float4*>(r);
                float  hv = *phi;
                w[d][0] = lo.x; w[d][1] = lo.y;
                w[d][2] = md.x; w[d][3] = md.y; w[d][4] = md.z; w[d][5] = md.w;
                w[d][6] = hv;
            } else {
                const float* plo = (r - 1 < f2lo) ? f2lo : (r - 1);
                float  lv = *plo;
                float4 md = *reinterpret_cast<const float4*>(r);
                w[d][0] = lv;
                w[d][1] = md.x; w[d][2] = md.y; w[d][3] = md.z; w[d][4] = md.w;
            }
        }
#pragma unroll
        for (int d = 0; d < NOFF; ++d)
#pragma unroll
            for (int dx = 0; dx < NOFF; ++dx)
#pragma unroll
                for (int p = 0; p < 4; ++p)
                    acc[d][dx][p] = fmaf(f1a[p], w[d][p + dx], acc[d][dx][p]);
    }

    float* ao = slices + ((size_t)(chunk * 2 + b) * NOFF * NOFF) * HW + px;
#pragma unroll
    for (int dyi = 0; dyi < NOFF; ++dyi)
#pragma unroll
        for (int dxi = 0; dxi < NOFF; ++dxi) {
            float v[4];
#pragma unroll
            for (int p = 0; p < 4; ++p) {
                int col = x0 + p + dxi - OFS;
                float m = (col >= 0 && col < W) ? rm[dyi] : 0.f;
                v[p] = acc[dyi][dxi][p] * m;
            }
            *reinterpret_cast<float4*>(ao + (size_t)(dyi * NOFF + dxi) * HW) =
                make_float4(v[0], v[1], v[2], v[3]);
        }
}

// ---------------- slice reduction: base[i] = sum_s slices[s*STRIDE + i] ------
template<int S, int STRIDE>
__global__ void reduce_kernel(const float* __restrict__ in, float* __restrict__ out) {
    const int i = (blockIdx.x * 256 + threadIdx.x) * 4;
    if (i >= STRIDE) return;
    float sx = 0.f, sy = 0.f, sz = 0.f, sw = 0.f;
#pragma unroll 8
    for (int k = 0; k < S; ++k) {
        float4 v = *reinterpret_cast<const float4*>(in + (size_t)k * STRIDE + i);
        sx += v.x; sy += v.y; sz += v.z; sw += v.w;
    }
    *reinterpret_cast<float4*>(out + i) = make_float4(sx, sy, sz, sw);
}

// ---------------- build conv input: Xin[b][icg16][y][x][ic16] bf16 -----------
template<int H, int W, int SCALE, int SHIFT, int NOFF, int OFS>
__global__ void xbuild_kernel(const float* __restrict__ base, const float* __restrict__ h_pre,
                              ushort* __restrict__ Xin) {
    const int HW = H * W;
    int i = blockIdx.x * 256 + threadIdx.x;
    if (i >= 2 * HW * 16) return;
    int g  = i & 15;                 // 8-ic group 0..15
    int px = (i >> 4) % HW;
    int b  = (i >> 4) / HW;
    int y = px / W, x = px - y * W;
    ushort out8[8];
#pragma unroll
    for (int j = 0; j < 8; ++j) {
        int ic = g * 8 + j;
        float v = 0.f;
        if (ic < 49) {
            int pi = ic / 7, pj = ic - pi * 7;
            int dy = pi - 3, dx = pj - 3;
            int uy = SCALE * y + dy, ux = SCALE * x + dx;
            if (uy >= 0 && uy < SCALE * H && ux >= 0 && ux < SCALE * W) {
                int idy = (dy >> SHIFT) + OFS;
                int idx = (dx >> SHIFT) + OFS;
                float cv = base[((size_t)b * NOFF * NOFF + idy * NOFF + idx) * HW + px];
                v = cv >= 0.f ? cv : 0.01f * cv;
            }
        } else if (ic < 98) {
            v = h_pre[((size_t)b * 49 + (ic - 49)) * HW + px];
        }
        out8[j] = f2bf(v);
    }
    size_t off = (((size_t)b * 8 + (g >> 1)) * HW + px) * 16 + (g & 1) * 8;
    *reinterpret_cast<uint4*>(Xin + off) = *reinterpret_cast<uint4*>(out8);
}

// ---------------- weight prep: Wmf[tap9][icg16][oc256][8] bf16 (both levels) ----
__global__ void wprep_kernel(const float* __restrict__ w0, const float* __restrict__ w1,
                             ushort* __restrict__ Wmf0, ushort* __restrict__ Wmf1) {
    const float* w = blockIdx.y ? w1 : w0;
    ushort* Wmf    = blockIdx.y ? Wmf1 : Wmf0;
    int i = blockIdx.x * 256 + threadIdx.x;
    const int n = 9 * 16 * 256 * 8;
    if (i >= n) return;
    int iEl = i & 7;
    int oc  = (i >> 3) & 255;
    int icg = (i >> 11) & 15;
    int tap = i >> 15;
    int ic  = icg * 8 + iEl;
    float v = (oc < 196 && ic < 98) ? w[((size_t)oc * 98 + ic) * 9 + tap] : 0.f;
    Wmf[i] = f2bf(v);
}

// ---------------- conv3x3 via mfma_f32_32x32x16_bf16, no LDS, no barriers ----
template<int H, int W, int SPLIT, int ICPS, int NKC>
__global__ __launch_bounds__(256, 2) void convmf_kernel(const ushort* __restrict__ Xin,
                                                        const ushort* __restrict__ Wmf,
                                                        float* __restrict__ Y) {
    const int HW = H * W;
    const int tilesx = W / 16;
    const int by0 = (blockIdx.x / tilesx) * 8;
    const int bx0 = (blockIdx.x % tilesx) * 16;
    const int ocb = blockIdx.y * 64;
    const int b   = blockIdx.z & 1;
    const int s   = blockIdx.z >> 1;
    const int t   = threadIdx.x;
    const int wv  = t >> 6;
    const int l   = t & 63;
    const int n    = l & 31;
    const int hi   = l >> 5;
    const int wrow = 2 * wv + (n >> 4);
    const int wcol = n & 15;

    f32x16 acc0 = {};
    f32x16 acc1 = {};

#pragma unroll
    for (int kc = 0; kc < NKC; ++kc) {
        const int icg8  = (s * ICPS + kc * 16) / 8 + hi;
        const int icg16 = (s * ICPS) / 16 + kc;
        const ushort* wp = Wmf + ((size_t)icg8 * 256 + ocb + n) * 8;
        const ushort* xb = Xin + ((size_t)b * 8 + icg16) * HW * 16 + hi * 8;
#pragma unroll
        for (int j = 0; j < 9; ++j) {
            const int ky = j / 3, kx = j - ky * 3;
            bf16x8 a0 = *reinterpret_cast<const bf16x8*>(wp + (size_t)j * 16 * 256 * 8);
            bf16x8 a1 = *reinterpret_cast<const bf16x8*>(wp + (size_t)j * 16 * 256 * 8 + 32 * 8);
            const int gy = by0 + wrow + ky - 1;
            const int gx = bx0 + wcol + kx - 1;
            bf16x8 bfr = {};
            if (gy >= 0 && gy < H && gx >= 0 && gx < W)
                bfr = *reinterpret_cast<const bf16x8*>(xb + (size_t)(gy * W + gx) * 16);
            acc0 = __builtin_amdgcn_mfma_f32_32x32x16_bf16(a0, bfr, acc0, 0, 0, 0);
            acc1 = __builtin_amdgcn_mfma_f32_32x32x16_bf16(a1, bfr, acc1, 0, 0, 0);
        }
    }

    float* Yo = Y + ((size_t)(s * 2 + b) * 196) * HW;
    const int po = (by0 + wrow) * W + bx0 + wcol;
#pragma unroll
    for (int r = 0; r < 16; ++r) {
        int m = (r & 3) + 8 * (r >> 2) + 4 * hi;
        int oc0 = ocb + m;
        if (oc0 < 196) Yo[(size_t)oc0 * HW + po] = acc0[r];
        int oc1 = ocb + 32 + m;
        if (oc1 < 196) Yo[(size_t)oc1 * HW + po] = acc1[r];
    }
}

// ---------------- LSTM gates (split-reduce + bias + elementwise) ----------------
template<int S, int HW>
__global__ void lstm_kernel(const float* __restrict__ Y, const float* __restrict__ bias,
                            const float* __restrict__ c_pre,
                            float* __restrict__ h_out, float* __restrict__ c_out) {
    int i = blockIdx.x * 256 + threadIdx.x;
    const int n = 2 * 49 * HW;
    if (i >= n) return;
    int b   = i / (49 * HW);
    int rem = i - b * (49 * HW);
    int k   = rem / HW;
    float g4[4];
#pragma unroll
    for (int gi = 0; gi < 4; ++gi) {
        float v = bias[gi * 49 + k];
#pragma unroll
        for (int ss = 0; ss < S; ++ss)
            v += Y[((size_t)((ss * 2 + b) * 196) + gi * 49) * HW + rem];
        g4[gi] = v;
    }
    float iv = sigmoidf_(g4[0]);
    float fv = sigmoidf_(g4[1]);
    float ov = sigmoidf_(g4[2]);
    float gv = tanhf(g4[3]);
    float cp = c_pre[i];
    float cn = fv * cp + iv * gv;
    h_out[i] = ov * tanhf(cn);
    c_out[i] = cn;
}

extern "C" void kernel_launch(void* const* d_in, const int* in_sizes, int n_in,
                              void* d_out, int out_size, void* d_ws, size_t ws_size,
                              hipStream_t stream) {
    (void)in_sizes; (void)n_in; (void)out_size; (void)ws_size;
    const float* x0  = (const float*)d_in[0];
    const float* x1  = (const float*)d_in[1];
    const float* xp0 = (const float*)d_in[2];
    const float* xp1 = (const float*)d_in[3];
    const float* h0  = (const float*)d_in[4];
    const float* c0  = (const float*)d_in[5];
    const float* h1  = (const float*)d_in[6];
    const float* c1  = (const float*)d_in[7];
    const float* w0  = (const float*)d_in[8];
    const float* b0  = (const float*)d_in[9];
    const float* w1  = (const float*)d_in[10];
    const float* b1  = (const float*)d_in[11];
    float* out = (float*)d_out;

    // workspace layout (floats) — 23.6 MB, same as rounds 5/6
    float* ws = (float*)d_ws;
    float*  Wmf0f = ws;                  // 147456
    float*  Wmf1f = Wmf0f + 147456;      // 147456
    float*  Xin0f = Wmf1f + 147456;      // 524288
    float*  Xin1f = Xin0f + 524288;      // 131072
    float*  base0 = Xin1f + 131072;      // 131072 (2b*16off*4096)
    float*  base1 = base0 + 131072;      // 8192   (2b*4off*1024)
    float*  Y0    = base1 + 8192;        // 3211264 (2sp*2b*196*4096)
    float*  Y1    = Y0 + 3211264;        // 1605632 (4sp*2b*196*1024)
    // corr slice buffers alias the Y region (consumed by reduce before conv writes Y)
    float*  slc0  = Y0;                  // 32 chunks * 2b*16off*4096 = 4194304
    float*  slc1  = Y0 + 4194304;        // 64 chunks * 2b*4off*1024  = 524288 (ends 4718592 <= 4816896)
    ushort* Wmf0 = (ushort*)Wmf0f;
    ushort* Wmf1 = (ushort*)Wmf1f;
    ushort* Xin0 = (ushort*)Xin0f;
    ushort* Xin1 = (ushort*)Xin1f;

    // level 0: C=512, CC=16 -> 32 chunks; level 1: C=1024, CC=16 -> 64 chunks
    corr_kernel<512, 16, 64, 64, 4, 2><<<dim3(4, 2, 32), 256, 0, stream>>>(x0, xp0, slc0);
    corr_kernel<1024, 16, 32, 32, 2, 1><<<dim3(1, 2, 64), 256, 0, stream>>>(x1, xp1, slc1);

    reduce_kernel<32, 131072><<<128, 256, 0, stream>>>(slc0, base0);
    reduce_kernel<64, 8192><<<8, 256, 0, stream>>>(slc1, base1);

    wprep_kernel<<<dim3(1152, 2), 256, 0, stream>>>(w0, w1, Wmf0, Wmf1);

    xbuild_kernel<64, 64, 2, 1, 4, 2><<<512, 256, 0, stream>>>(base0, h0, Xin0);
    xbuild_kernel<32, 32, 4, 2, 2, 1><<<128, 256, 0, stream>>>(base1, h1, Xin1);

    convmf_kernel<64, 64, 2, 64, 4><<<dim3(32, 4, 4), 256, 0, stream>>>(Xin0, Wmf0, Y0);
    convmf_kernel<32, 32, 4, 32, 2><<<dim3(8, 4, 8), 256, 0, stream>>>(Xin1, Wmf1, Y1);

    lstm_kernel<2, 4096><<<1568, 256, 0, stream>>>(Y0, b0, c0, out + 0,      out + 401408);
    lstm_kernel<4, 1024><<<392,  256, 0, stream>>>(Y1, b1, c1, out + 802816, out + 903168);
}

// Round 10
// 186.741 us; speedup vs baseline: 1.7006x; 1.0141x over previous
//
#include <hip/hip_runtime.h>

#define DEVFN __device__ __forceinline__

typedef __attribute__((ext_vector_type(8))) __bf16 bf16x8;
typedef __attribute__((ext_vector_type(16))) float f32x16;
typedef unsigned short ushort;

DEVFN float sigmoidf_(float x) { return 1.f / (1.f + __expf(-x)); }

DEVFN ushort f2bf(float f) {   // RNE float->bf16
    unsigned u = __float_as_uint(f);
    unsigned r = (u + 0x7FFF + ((u >> 16) & 1)) >> 16;
    return (ushort)r;
}

// ---------------- correlation: clamped loads, masked store, 2 blocks/CU ------
// Thread owns 4 px. Per channel, per dy: {float2,float4,scalar} clamped loads
// consumed immediately (small live set). OOB garbage zeroed by mask at store.
template<int C, int CC, int H, int W, int NOFF, int OFS>
__global__ __launch_bounds__(256, 2) void corr_kernel(const float* __restrict__ f1,
                                                      const float* __restrict__ f2,
                                                      float* __restrict__ slices) {
    constexpr int HW = H * W;
    constexpr int WIN = NOFF + 3;
    const int t     = threadIdx.x;
    const int px    = blockIdx.x * 1024 + t * 4;
    const int b     = blockIdx.y;
    const int chunk = blockIdx.z;
    const int y  = px / W;
    const int x0 = px - y * W;

    const float* f1p    = f1 + ((size_t)b * C + chunk * CC) * HW + px;
    const float* f2b    = f2 + ((size_t)b * C + chunk * CC) * HW;
    const float* f2lo   = f2;
    const float* f2hi   = f2 + (size_t)2 * C * HW - 2;

    int   yc[NOFF];
    float rm[NOFF];
#pragma unroll
    for (int d = 0; d < NOFF; ++d) {
        int yy = y + d - OFS;
        rm[d] = (yy >= 0 && yy < H) ? 1.f : 0.f;
        yc[d] = yy < 0 ? 0 : (yy >= H ? H - 1 : yy);
    }

    float acc[NOFF][NOFF][4];
#pragma unroll
    for (int i = 0; i < NOFF; ++i)
#pragma unroll
        for (int j = 0; j < NOFF; ++j)
#pragma unroll
            for (int p = 0; p < 4; ++p) acc[i][j][p] = 0.f;

#pragma unroll 2
    for (int c = 0; c < CC; ++c) {
        float f1a[4];
        *reinterpret_cast<float4*>(f1a) = *reinterpret_cast<const float4*>(f1p + (size_t)c * HW);
#pragma unroll
        for (int d = 0; d < NOFF; ++d) {
            const float* r = f2b + (size_t)c * HW + yc[d] * W + x0;
            float w[WIN];
            if constexpr (OFS == 2) {
                const float* plo = (r - 2 < f2lo) ? f2lo : (r - 2);
                const float* phi = (r + 4 > f2hi) ? f2hi : (r + 4);
                float2 lo = *reinterpret_cast<const float2*>(plo);
                float4 md = *reinterpret_cast<const float4*>(r);
                float  hv = *phi;
                w[0] = lo.x; w[1] = lo.y;
                w[2] = md.x; w[3] = md.y; w[4] = md.z; w[5] = md.w;
                w[6] = hv;
            } else {
                const float* plo = (r - 1 < f2lo) ? f2lo : (r - 1);
                float  lv = *plo;
                float4 md = *reinterpret_cast<const float4*>(r);
                w[0] = lv;
                w[1] = md.x; w[2] = md.y; w[3] = md.z; w[4] = md.w;
            }
#pragma unroll
            for (int dx = 0; dx < NOFF; ++dx)
#pragma unroll
                for (int p = 0; p < 4; ++p)
                    acc[d][dx][p] = fmaf(f1a[p], w[p + dx], acc[d][dx][p]);
        }
    }

    float* ao = slices + ((size_t)(chunk * 2 + b) * NOFF * NOFF) * HW + px;
#pragma unroll
    for (int dyi = 0; dyi < NOFF; ++dyi)
#pragma unroll
        for (int dxi = 0; dxi < NOFF; ++dxi) {
            float v[4];
#pragma unroll
            for (int p = 0; p < 4; ++p) {
                int col = x0 + p + dxi - OFS;
                float m = (col >= 0 && col < W) ? rm[dyi] : 0.f;
                v[p] = acc[dyi][dxi][p] * m;
            }
            *reinterpret_cast<float4*>(ao + (size_t)(dyi * NOFF + dxi) * HW) =
                make_float4(v[0], v[1], v[2], v[3]);
        }
}

// ---------------- slice reduction: base[i] = sum_s slices[s*STRIDE + i] ------
template<int S, int STRIDE>
__global__ void reduce_kernel(const float* __restrict__ in, float* __restrict__ out) {
    const int i = (blockIdx.x * 256 + threadIdx.x) * 4;
    if (i >= STRIDE) return;
    float sx = 0.f, sy = 0.f, sz = 0.f, sw = 0.f;
#pragma unroll 8
    for (int k = 0; k < S; ++k) {
        float4 v = *reinterpret_cast<const float4*>(in + (size_t)k * STRIDE + i);
        sx += v.x; sy += v.y; sz += v.z; sw += v.w;
    }
    *reinterpret_cast<float4*>(out + i) = make_float4(sx, sy, sz, sw);
}

// ---------------- build conv input: Xin[b][icg16][y][x][ic16] bf16 -----------
template<int H, int W, int SCALE, int SHIFT, int NOFF, int OFS>
__global__ void xbuild_kernel(const float* __restrict__ base, const float* __restrict__ h_pre,
                              ushort* __restrict__ Xin) {
    const int HW = H * W;
    int i = blockIdx.x * 256 + threadIdx.x;
    if (i >= 2 * HW * 16) return;
    int g  = i & 15;
    int px = (i >> 4) % HW;
    int b  = (i >> 4) / HW;
    int y = px / W, x = px - y * W;
    ushort out8[8];
#pragma unroll
    for (int j = 0; j < 8; ++j) {
        int ic = g * 8 + j;
        float v = 0.f;
        if (ic < 49) {
            int pi = ic / 7, pj = ic - pi * 7;
            int dy = pi - 3, dx = pj - 3;
            int uy = SCALE * y + dy, ux = SCALE * x + dx;
            if (uy >= 0 && uy < SCALE * H && ux >= 0 && ux < SCALE * W) {
                int idy = (dy >> SHIFT) + OFS;
                int idx = (dx >> SHIFT) + OFS;
                float cv = base[((size_t)b * NOFF * NOFF + idy * NOFF + idx) * HW + px];
                v = cv >= 0.f ? cv : 0.01f * cv;
            }
        } else if (ic < 98) {
            v = h_pre[((size_t)b * 49 + (ic - 49)) * HW + px];
        }
        out8[j] = f2bf(v);
    }
    size_t off = (((size_t)b * 8 + (g >> 1)) * HW + px) * 16 + (g & 1) * 8;
    *reinterpret_cast<uint4*>(Xin + off) = *reinterpret_cast<uint4*>(out8);
}

// ---------------- weight prep: Wmf[tap9][icg16][oc256][8] bf16 (both levels) ----
__global__ void wprep_kernel(const float* __restrict__ w0, const float* __restrict__ w1,
                             ushort* __restrict__ Wmf0, ushort* __restrict__ Wmf1) {
    const float* w = blockIdx.y ? w1 : w0;
    ushort* Wmf    = blockIdx.y ? Wmf1 : Wmf0;
    int i = blockIdx.x * 256 + threadIdx.x;
    const int n = 9 * 16 * 256 * 8;
    if (i >= n) return;
    int iEl = i & 7;
    int oc  = (i >> 3) & 255;
    int icg = (i >> 11) & 15;
    int tap = i >> 15;
    int ic  = icg * 8 + iEl;
    float v = (oc < 196 && ic < 98) ? w[((size_t)oc * 98 + ic) * 9 + tap] : 0.f;
    Wmf[i] = f2bf(v);
}

// ---------------- conv3x3 via mfma_f32_32x32x16_bf16, 2 px-tiles/wave --------
// Block: 64 oc x (8 rows x 32 cols). Per j: 2 W-frags + 2 X-frags -> 4 MFMA.
template<int H, int W, int SPLIT, int ICPS, int NKC>
__global__ __launch_bounds__(256, 2) void convmf_kernel(const ushort* __restrict__ Xin,
                                                        const ushort* __restrict__ Wmf,
                                                        float* __restrict__ Y) {
    const int HW = H * W;
    const int tilesx = W / 32;
    const int by0 = (blockIdx.x / tilesx) * 8;
    const int bx0 = (blockIdx.x % tilesx) * 32;
    const int ocb = blockIdx.y * 64;
    const int b   = blockIdx.z & 1;
    const int s   = blockIdx.z >> 1;
    const int t   = threadIdx.x;
    const int wv  = t >> 6;
    const int l   = t & 63;
    const int n    = l & 31;
    const int hi   = l >> 5;
    const int wrow = 2 * wv + (n >> 4);
    const int wcol = n & 15;

    f32x16 acc00 = {}, acc10 = {}, acc01 = {}, acc11 = {};

#pragma unroll
    for (int kc = 0; kc < NKC; ++kc) {
        const int icg8  = (s * ICPS + kc * 16) / 8 + hi;
        const int icg16 = (s * ICPS) / 16 + kc;
        const ushort* wp = Wmf + ((size_t)icg8 * 256 + ocb + n) * 8;
        const ushort* xb = Xin + (((size_t)b * 8 + icg16) * HW) * 16 + hi * 8;
#pragma unroll
        for (int j = 0; j < 9; ++j) {
            const int ky = j / 3, kx = j - ky * 3;
            bf16x8 a0 = *reinterpret_cast<const bf16x8*>(wp + (size_t)j * 16 * 256 * 8);
            bf16x8 a1 = *reinterpret_cast<const bf16x8*>(wp + (size_t)j * 16 * 256 * 8 + 32 * 8);
            const int gy  = by0 + wrow + ky - 1;
            const int gx0 = bx0 + wcol + kx - 1;
            const int gx1 = gx0 + 16;
            const bool yok = (gy >= 0) && (gy < H);
            bf16x8 bf0 = {}, bf1 = {};
            if (yok && gx0 >= 0 && gx0 < W) bf0 = *reinterpret_cast<const bf16x8*>(xb + (size_t)(gy * W + gx0) * 16);
            if (yok && gx1 < W)             bf1 = *reinterpret_cast<const bf16x8*>(xb + (size_t)(gy * W + gx1) * 16);
            acc00 = __builtin_amdgcn_mfma_f32_32x32x16_bf16(a0, bf0, acc00, 0, 0, 0);
            acc10 = __builtin_amdgcn_mfma_f32_32x32x16_bf16(a1, bf0, acc10, 0, 0, 0);
            acc01 = __builtin_amdgcn_mfma_f32_32x32x16_bf16(a0, bf1, acc01, 0, 0, 0);
            acc11 = __builtin_amdgcn_mfma_f32_32x32x16_bf16(a1, bf1, acc11, 0, 0, 0);
        }
    }

    float* Yo = Y + ((size_t)(s * 2 + b) * 196) * HW;
    const int po = (by0 + wrow) * W + bx0 + wcol;
#pragma unroll
    for (int r = 0; r < 16; ++r) {
        int m = (r & 3) + 8 * (r >> 2) + 4 * hi;
        int oc0 = ocb + m;
        int oc1 = ocb + 32 + m;
        if (oc0 < 196) {
            Yo[(size_t)oc0 * HW + po]      = acc00[r];
            Yo[(size_t)oc0 * HW + po + 16] = acc01[r];
        }
        if (oc1 < 196) {
            Yo[(size_t)oc1 * HW + po]      = acc10[r];
            Yo[(size_t)oc1 * HW + po + 16] = acc11[r];
        }
    }
}

// ---------------- LSTM gates (split-reduce + bias + elementwise) ----------------
template<int S, int HW>
__global__ void lstm_kernel(const float* __restrict__ Y, const float* __restrict__ bias,
                            const float* __restrict__ c_pre,
                            float* __restrict__ h_out, float* __restrict__ c_out) {
    int i = blockIdx.x * 256 + threadIdx.x;
    const int n = 2 * 49 * HW;
    if (i >= n) return;
    int b   = i / (49 * HW);
    int rem = i - b * (49 * HW);
    int k   = rem / HW;
    float g4[4];
#pragma unroll
    for (int gi = 0; gi < 4; ++gi) {
        float v = bias[gi * 49 + k];
#pragma unroll
        for (int ss = 0; ss < S; ++ss)
            v += Y[((size_t)((ss * 2 + b) * 196) + gi * 49) * HW + rem];
        g4[gi] = v;
    }
    float iv = sigmoidf_(g4[0]);
    float fv = sigmoidf_(g4[1]);
    float ov = sigmoidf_(g4[2]);
    float gv = tanhf(g4[3]);
    float cp = c_pre[i];
    float cn = fv * cp + iv * gv;
    h_out[i] = ov * tanhf(cn);
    c_out[i] = cn;
}

extern "C" void kernel_launch(void* const* d_in, const int* in_sizes, int n_in,
                              void* d_out, int out_size, void* d_ws, size_t ws_size,
                              hipStream_t stream) {
    (void)in_sizes; (void)n_in; (void)out_size; (void)ws_size;
    const float* x0  = (const float*)d_in[0];
    const float* x1  = (const float*)d_in[1];
    const float* xp0 = (const float*)d_in[2];
    const float* xp1 = (const float*)d_in[3];
    const float* h0  = (const float*)d_in[4];
    const float* c0  = (const float*)d_in[5];
    const float* h1  = (const float*)d_in[6];
    const float* c1  = (const float*)d_in[7];
    const float* w0  = (const float*)d_in[8];
    const float* b0  = (const float*)d_in[9];
    const float* w1  = (const float*)d_in[10];
    const float* b1  = (const float*)d_in[11];
    float* out = (float*)d_out;

    // workspace layout (floats) — ~81 MB of the 256 MiB d_ws, no aliasing
    float* ws = (float*)d_ws;
    float*  Wmf0f = ws;                   // 147456
    float*  Wmf1f = Wmf0f + 147456;       // 147456
    float*  Xin0f = Wmf1f + 147456;       // 524288
    float*  Xin1f = Xin0f + 524288;       // 131072
    float*  base0 = Xin1f + 131072;       // 131072 (2b*16off*4096)
    float*  base1 = base0 + 131072;       // 8192   (2b*4off*1024)
    float*  slc0  = base1 + 8192;         // 64ch*2b*16off*4096 = 8388608
    float*  slc1  = slc0 + 8388608;       // 128ch*2b*4off*1024 = 1048576
    float*  Y0    = slc1 + 1048576;       // 4sp*2b*196*4096 = 6422528
    float*  Y1    = Y0 + 6422528;         // 8sp*2b*196*1024 = 3211264
    ushort* Wmf0 = (ushort*)Wmf0f;
    ushort* Wmf1 = (ushort*)Wmf1f;
    ushort* Xin0 = (ushort*)Xin0f;
    ushort* Xin1 = (ushort*)Xin1f;

    // level 0: C=512, CC=8 -> 64 chunks (512 blocks); level 1: CC=8 -> 128 chunks (256 blocks)
    corr_kernel<512, 8, 64, 64, 4, 2><<<dim3(4, 2, 64), 256, 0, stream>>>(x0, xp0, slc0);
    corr_kernel<1024, 8, 32, 32, 2, 1><<<dim3(1, 2, 128), 256, 0, stream>>>(x1, xp1, slc1);

    reduce_kernel<64, 131072><<<128, 256, 0, stream>>>(slc0, base0);
    reduce_kernel<128, 8192><<<8, 256, 0, stream>>>(slc1, base1);

    wprep_kernel<<<dim3(1152, 2), 256, 0, stream>>>(w0, w1, Wmf0, Wmf1);

    xbuild_kernel<64, 64, 2, 1, 4, 2><<<512, 256, 0, stream>>>(base0, h0, Xin0);
    xbuild_kernel<32, 32, 4, 2, 2, 1><<<128, 256, 0, stream>>>(base1, h1, Xin1);

    // conv level 0: SPLIT=4 (32 ic), NKC=2; grid (16 px-tiles, 4 ocb, 2b*4s) = 512 blocks
    convmf_kernel<64, 64, 4, 32, 2><<<dim3(16, 4, 8), 256, 0, stream>>>(Xin0, Wmf0, Y0);
    // conv level 1: SPLIT=8 (16 ic), NKC=1; grid (4 px-tiles, 4 ocb, 2b*8s) = 256 blocks
    convmf_kernel<32, 32, 8, 16, 1><<<dim3(4, 4, 16), 256, 0, stream>>>(Xin1, Wmf1, Y1);

    lstm_kernel<4, 4096><<<1568, 256, 0, stream>>>(Y0, b0, c0, out + 0,      out + 401408);
    lstm_kernel<8, 1024><<<392,  256, 0, stream>>>(Y1, b1, c1, out + 802816, out + 903168);
}